// Round 1
// baseline (45.066 us; speedup 1.0000x reference)
//
#include <hip/hip_runtime.h>

// ConvCaps2D with dynamic routing, fused single kernel.
// B=8, H=W=32, Cin=16, pose 4x4, kernel 3x3 stride 2 VALID -> oh=ow=15,
// O=16 out channels, N=144 votes, 3 routing iterations.
// One block (256 threads) per output site (b,h,w): thread t owns
// (o = t>>4, n = (t&15)+16j, j=0..8) -> 9 votes of 16 f32 in registers.

#define OH 15
#define OW 15
#define N_VOTES 144
#define VPT 9            // votes per thread: 16*144/256
#define POSE_PAD 20      // LDS row stride for pose rows (16 floats + pad)
#define B_PAD 17         // LDS row stride for b[n][o]

__global__ __launch_bounds__(256, 2)
void convcaps_routing_kernel(const float* __restrict__ poses,
                             const float* __restrict__ kern,
                             float* __restrict__ out)
{
    __shared__ float pose_lds[N_VOTES * POSE_PAD]; // 11520 B
    __shared__ float b_lds[N_VOTES * B_PAD];       // 9792 B
    __shared__ float nmax[N_VOTES];                // softmax max per n
    __shared__ float rden[N_VOTES];                // 1/sum(exp) per n

    const int site = blockIdx.x;                   // 0..1799
    const int b    = site / (OH * OW);
    const int rem  = site % (OH * OW);
    const int h    = rem / OW;
    const int w    = rem % OW;

    const int t  = threadIdx.x;
    const int o  = t >> 4;                         // output channel 0..15
    const int nt = t & 15;                         // base vote index

    // ---- stage 144 pose matrices (16 f32 each) into LDS, float4 coalesced ----
    // poses[b][y][x][c][p][q], y = 2h+k, x = 2w+l, n = (3k+l)*16 + c
    const float* pbase = poses + (size_t)b * (32 * 32 * 256);
    for (int idx = t; idx < N_VOTES * 4; idx += 256) {
        int n  = idx >> 2;
        int e4 = idx & 3;
        int kl = n >> 4;          // 0..8
        int c  = n & 15;
        int k  = kl / 3, l = kl % 3;
        int y  = 2 * h + k, x = 2 * w + l;
        const float4 v = *reinterpret_cast<const float4*>(
            pbase + (size_t)(y * 32 + x) * 256 + c * 16 + e4 * 4);
        *reinterpret_cast<float4*>(&pose_lds[n * POSE_PAD + e4 * 4]) = v;
    }
    __syncthreads();

    // ---- votes into registers: vote[p][r] = sum_q pose[p][q] * K[q][r] ----
    float vreg[VPT][16];
    #pragma unroll
    for (int j = 0; j < VPT; ++j) {
        const int n = nt + 16 * j;
        const float* Kp = kern + ((size_t)(o * N_VOTES + n) << 4);
        const float4 k0 = reinterpret_cast<const float4*>(Kp)[0];
        const float4 k1 = reinterpret_cast<const float4*>(Kp)[1];
        const float4 k2 = reinterpret_cast<const float4*>(Kp)[2];
        const float4 k3 = reinterpret_cast<const float4*>(Kp)[3];
        const float* P = &pose_lds[n * POSE_PAD];
        #pragma unroll
        for (int p = 0; p < 4; ++p) {
            const float p0 = P[p * 4 + 0], p1 = P[p * 4 + 1];
            const float p2 = P[p * 4 + 2], p3 = P[p * 4 + 3];
            vreg[j][p * 4 + 0] = p0 * k0.x + p1 * k1.x + p2 * k2.x + p3 * k3.x;
            vreg[j][p * 4 + 1] = p0 * k0.y + p1 * k1.y + p2 * k2.y + p3 * k3.y;
            vreg[j][p * 4 + 2] = p0 * k0.z + p1 * k1.z + p2 * k2.z + p3 * k3.z;
            vreg[j][p * 4 + 3] = p0 * k0.w + p1 * k1.w + p2 * k2.w + p3 * k3.w;
        }
    }

    float breg[VPT];
    #pragma unroll
    for (int j = 0; j < VPT; ++j) breg[j] = 0.0f;

    float vfin[16];

    #pragma unroll
    for (int iter = 0; iter < 3; ++iter) {
        // coupling coefficients c[o][n] = softmax_o(b)
        float c_[VPT];
        if (iter == 0) {
            #pragma unroll
            for (int j = 0; j < VPT; ++j) c_[j] = 1.0f / 16.0f;   // softmax of zeros
        } else {
            #pragma unroll
            for (int j = 0; j < VPT; ++j) {
                const int n = nt + 16 * j;
                c_[j] = __expf(breg[j] - nmax[n]) * rden[n];
            }
        }

        // s[o] = sum_n c * vote : per-thread partial then 16-lane butterfly
        float s[16];
        #pragma unroll
        for (int e = 0; e < 16; ++e) s[e] = 0.0f;
        #pragma unroll
        for (int j = 0; j < VPT; ++j) {
            #pragma unroll
            for (int e = 0; e < 16; ++e) s[e] += c_[j] * vreg[j][e];
        }
        #pragma unroll
        for (int m = 1; m <= 8; m <<= 1) {
            #pragma unroll
            for (int e = 0; e < 16; ++e) s[e] += __shfl_xor(s[e], m, 64);
        }
        // after butterfly all 16 lanes of this o-group hold the full s[o]

        // squash: v = s * (sq/(1+sq)) / sqrt(sq + 1e-9)
        float sq = 0.0f;
        #pragma unroll
        for (int e = 0; e < 16; ++e) sq += s[e] * s[e];
        const float factor = (sq / (1.0f + sq)) * rsqrtf(sq + 1e-9f);
        #pragma unroll
        for (int e = 0; e < 16; ++e) vfin[e] = s[e] * factor;

        if (iter < 2) {
            // b[o][n] += dot(v[o], vote[o][n]); publish b for softmax stats
            #pragma unroll
            for (int j = 0; j < VPT; ++j) {
                float d = 0.0f;
                #pragma unroll
                for (int e = 0; e < 16; ++e) d += vfin[e] * vreg[j][e];
                breg[j] += d;
                b_lds[(nt + 16 * j) * B_PAD + o] = breg[j];
            }
            __syncthreads();
            if (t < N_VOTES) {
                float mx = -1e30f;
                #pragma unroll
                for (int oo = 0; oo < 16; ++oo)
                    mx = fmaxf(mx, b_lds[t * B_PAD + oo]);
                float sum = 0.0f;
                #pragma unroll
                for (int oo = 0; oo < 16; ++oo)
                    sum += __expf(b_lds[t * B_PAD + oo] - mx);
                nmax[t] = mx;
                rden[t] = 1.0f / sum;
            }
            __syncthreads();
        }
    }

    // ---- output ----
    // capsule_poses: [8,15,15,16,4,4] flat: site*256 + o*16 + e ; thread t -> elem t
    float vout = vfin[0];
    #pragma unroll
    for (int e = 1; e < 16; ++e) {
        if (nt == e) vout = vfin[e];
    }
    out[(size_t)site * 256 + t] = vout;

    // capsule_activations: [8,15,15,16] after poses (460800 floats)
    if (nt == 0) {
        float sqv = 0.0f;
        #pragma unroll
        for (int e = 0; e < 16; ++e) sqv += vfin[e] * vfin[e];
        out[460800 + (size_t)site * 16 + o] = sqrtf(sqv + 1e-12f);
    }
}

extern "C" void kernel_launch(void* const* d_in, const int* in_sizes, int n_in,
                              void* d_out, int out_size, void* d_ws, size_t ws_size,
                              hipStream_t stream) {
    const float* poses = (const float*)d_in[0];   // [8,32,32,16,4,4] f32
    // d_in[1] = input_activations: unused by the reference computation
    const float* kern  = (const float*)d_in[2];   // [16,3,3,16,4,4] f32
    float* outp = (float*)d_out;                  // 460800 poses + 28800 activations

    convcaps_routing_kernel<<<dim3(8 * OH * OW), dim3(256), 0, stream>>>(
        poses, kern, outp);
}